// Round 7
// baseline (2702.053 us; speedup 1.0000x reference)
//
#include <hip/hip_runtime.h>
#include <math.h>

#define T_TOTAL   1000
#define BATCH     256
#define NH        256
#define NIN       85

static constexpr float SIGMA_C = 0.15811388300841897f;  // sqrt(2/0.2)*0.05
static constexpr float ALPHA_C = 0.2f;

using half4   = __attribute__((ext_vector_type(4))) _Float16;
using half8   = __attribute__((ext_vector_type(8))) _Float16;
using f32x4   = __attribute__((ext_vector_type(4))) float;

// workspace layout
#define GXEG_F    ((size_t)(T_TOTAL+1)*16*32*256)   // f32 gate preacts: [t][R][tau(32)][lane][4] = 525MB
#define GXEE_US   ((size_t)(T_TOTAL+1)*16*8*512)    // f16 E tiles: [t][R][w(8)][lane][8] = 131MB
#define WPACK_US  (8u*6u*8u*64u*8u)                 // recurrent-weight B-fragments (f16 bits)
#define WXPACK_US (48u*3u*64u*8u)                   // x-weight B-fragments (K padded 85->96)

__device__ __forceinline__ unsigned short f2h(float f){
  _Float16 h = (_Float16)f;
  return __builtin_bit_cast(unsigned short, h);
}

__device__ __forceinline__ void gload_lds16(const void* g, void* l){
  __builtin_amdgcn_global_load_lds((const __attribute__((address_space(1))) void*)g,
                                   (__attribute__((address_space(3))) void*)l, 16, 0, 0);
}

// Inline-asm MFMA with hard arch-VGPR constraints.
// Hazard discipline (compiler can't see inside asm, so we pad manually):
//  - chain-head variants carry a leading s_nop 1 (VALU-write->MFMA-read, 2 states)
//  - phase-B head uses literal-0 srcC (no VALU zero-init at all)
//  - after each cluster, a register-tied s_nop fence precedes any VALU read
#define MFMA16(acc, a, b) \
  asm("v_mfma_f32_16x16x32_f16 %0, %1, %2, %0" : "+v"(acc) : "v"(a), "v"(b))
#define MFMA16_F(acc, a, b) \
  asm("s_nop 1\n\tv_mfma_f32_16x16x32_f16 %0, %1, %2, %0" : "+v"(acc) : "v"(a), "v"(b))
#define MFMA16_Z(acc, a, b) \
  asm("s_nop 1\n\tv_mfma_f32_16x16x32_f16 %0, %1, %2, 0" : "=&v"(acc) : "v"(a), "v"(b))

// ---------------- k0: pack weights into MFMA B-fragment order (f16) ----------------
__global__ void k0_pack(const float* __restrict__ gk, const float* __restrict__ ck,
                        unsigned short* __restrict__ wpack, unsigned short* __restrict__ wxpack){
  int tid = blockIdx.x*256 + threadIdx.x;
  if (tid < (int)WPACK_US) {
    int j = tid & 7, l = (tid >> 3) & 63, kt = (tid >> 9) & 7, wt = tid >> 12;
    int w = wt / 6, tile = wt - 6*w;
    int lrow = l & 15, lquad = l >> 4;
    int k = kt*32 + lquad*8 + j;            // hidden index 0..255
    int tau = 2*w + (tile & 1);             // n-tile 0..15
    int kind = tile >> 1;                   // 0=r, 1=u, 2=c
    float v;
    if (kind == 0)      v = gk[(size_t)(85 + k)*512 + 16*tau + lrow];
    else if (kind == 1) v = gk[(size_t)(85 + k)*512 + 256 + 16*tau + lrow];
    else                v = ck[(size_t)(85 + k)*256 + 16*tau + lrow];
    wpack[tid] = f2h(v);
  } else if (tid < (int)(WPACK_US + WXPACK_US)) {
    int f = tid - (int)WPACK_US;
    int j = f & 7, l = (f >> 3) & 63, r = f >> 9;   // r = tau*3 + kt
    int kt = r % 3, tau = r / 3;
    int lrow = l & 15, lquad = l >> 4;
    int k = kt*32 + lquad*8 + j;            // x index, pad >=85 -> 0
    float v = 0.0f;
    if (k < NIN) {
      if (tau < 32) v = gk[(size_t)k*512 + 16*tau + lrow];
      else          v = ck[(size_t)k*256 + 16*(tau-32) + lrow];
    }
    wxpack[f] = f2h(v);
  }
}

// ---------------- k1: gxe precompute, ONE dispatch over all T ----------------
// gates (tau<32) -> f32 gxe[t][R][tau][lane][4]; E (tau>=32) -> f16 gxeE[t][R][w][lane][8]
__global__ __launch_bounds__(256) void k1_gxe(const float* __restrict__ x, const float* __restrict__ nz,
                       const float* __restrict__ gb, const float* __restrict__ cb,
                       const unsigned short* __restrict__ wxpack, float* __restrict__ gxe,
                       unsigned short* __restrict__ gxeE){
  int R  = blockIdx.x;
  int t  = blockIdx.y;
  int tid = threadIdx.x;
  __shared__ _Float16 xA[16][104];           // 96 K (padded) + 8 pad
  {
    int r = tid >> 4, c0 = tid & 15;
    const float* xrow = x + ((size_t)t*BATCH + 16*R + r)*NIN;
    for (int c = c0; c < 96; c += 16)
      xA[r][c] = (_Float16)(c < NIN ? xrow[c] : 0.0f);
  }
  __syncthreads();
  int l = tid & 63, wv = tid >> 6;
  int lrow = l & 15, lquad = l >> 4;
  const half8* xA8 = (const half8*)xA;       // row stride 104 f16 = 13 half8
  half8 afr[3];
  #pragma unroll
  for (int kt = 0; kt < 3; ++kt)
    afr[kt] = xA8[lrow*13 + kt*4 + lquad];
  const half8* wx8 = (const half8*)wxpack;
  for (int u = 0; u < 12; ++u) {
    int tau = wv + 4*u;                      // balanced: each wave gets 4 cand tiles
    f32x4 acc;
    if (tau < 32) {
      float b = gb[16*tau + lrow];
      acc = (f32x4){b, b, b, b};
    } else {
      int nc = 16*(tau-32) + lrow;
      float b = cb[nc];
      #pragma unroll
      for (int i = 0; i < 4; ++i)
        acc[i] = fmaf(SIGMA_C, nz[((size_t)t*BATCH + 16*R + lquad*4 + i)*NH + nc], b);
    }
    #pragma unroll
    for (int kt = 0; kt < 3; ++kt)
      acc = __builtin_amdgcn_mfma_f32_16x16x32_f16(afr[kt], wx8[((size_t)tau*3 + kt)*64 + l], acc, 0, 0, 0);
    if (tau < 32) {
      *(f32x4*)(gxe + ((((size_t)t*16 + R)*32 + tau)*64 + (size_t)l)*4) = acc;
    } else {
      int e = tau - 32, w2 = e >> 1, pp = e & 1;
      half4 o = {(_Float16)acc[0], (_Float16)acc[1], (_Float16)acc[2], (_Float16)acc[3]};
      *(half4*)(gxeE + ((((size_t)t*16 + R)*8 + w2)*64 + (size_t)l)*8 + pp*4) = o;
    }
  }
}

// ---------------- k2: ONE persistent recurrent scan over all 1000 steps ----------------
// 16 WGs x 8 waves. WG R owns batch rows [16R,16R+16); wave w owns n-cols [32w,32w+32).
// cand = cx + (r .* h) @ Wc_h + sigma*n  (r applied BEFORE the matmul).
// All 48 MFMAs are inline asm with hard "v" constraints (weights+accs forced into
// arch VGPRs; R4/R5: 128V/128A split shuttled every use). MFMA hazards padded
// manually (see macros + register-tied fences).
__global__ __launch_bounds__(512, 2) void k2_rec(const float* __restrict__ hin,
                       const unsigned short* __restrict__ wpack,
                       const float* __restrict__ gxe,
                       const unsigned short* __restrict__ gxeE,
                       float* __restrict__ out){
  int R = blockIdx.x;
  int tid = threadIdx.x;
  int l = tid & 63, w = tid >> 6;
  int lrow = l & 15, lquad = l >> 4;

  __shared__ float    gst[8*4*256];          // [w][gate tile q(4)][lane][4] f32, 32KB (DMA dest)
  __shared__ _Float16 hA[16][264];           // h f16  [row][n], stride 264
  __shared__ _Float16 rhA[16][264];          // r.*h f16, same layout

  { // init hA
    int r = tid >> 5, c0 = (tid & 31)*8;
    const float* hrow = hin + ((size_t)(16*R + r))*NH + c0;
    #pragma unroll
    for (int i = 0; i < 8; ++i)
      hA[r][c0+i] = (_Float16)hrow[i];
  }
  float hreg[2][4];                          // h f32, lane-private (rows lquad*4+i, cols 32w+16p+lrow)
  #pragma unroll
  for (int p = 0; p < 2; ++p)
    #pragma unroll
    for (int i = 0; i < 4; ++i)
      hreg[p][i] = hin[(size_t)(16*R + lquad*4 + i)*NH + 32*w + 16*p + lrow];

  // resident weight fragments (192 VGPRs; all uses are "v"-constrained asm)
  half8 wf[6][8];
  const half8* wp8 = (const half8*)wpack;
  #pragma unroll
  for (int tile = 0; tile < 6; ++tile)
    #pragma unroll
    for (int kt = 0; kt < 8; ++kt)
      wf[tile][kt] = wp8[((w*6 + tile)*8 + kt)*64 + l];

  // gate staging: tile q -> tau = 2w + {0,1,16,17} within the 32 gate tiles
  const size_t gstep  = (size_t)16*32*256;   // floats per time step
  const float* gsrc   = gxe + ((size_t)R*32 + 2*w)*256 + (size_t)l*4;   // per-lane DMA src
  float* lbase = gst + (size_t)w*4*256;                                  // wave-uniform LDS dest
  unsigned sb_addr = (unsigned)(unsigned long long)(const void*)lbase + (unsigned)l*16u;
  // E sidecar: one dwordx4 of f16x8 per step
  const half8* gE = (const half8*)(gxeE + (((size_t)R*8 + w)*64 + (size_t)l)*8);
  const size_t estep8 = (size_t)16*8*64;     // half8 units per time step

  // prologue: stage step-0 gates, load E(0); __syncthreads drains everything once
  gload_lds16(gsrc,             lbase);
  gload_lds16(gsrc +  1*256,    lbase + 1*256);
  gload_lds16(gsrc + 16*256,    lbase + 2*256);
  gload_lds16(gsrc + 17*256,    lbase + 3*256);
  half8 eh = gE[0];
  __syncthreads();

  const half8* hA8  = (const half8*)hA;      // row stride 33 half8
  const half8* rhA8 = (const half8*)rhA;
  float* outp = out + ((size_t)(16*R + lquad*4))*NH + 32*w + lrow;

  for (int t = 0; t < T_TOTAL; ++t) {
    // gate preacts: wait own DMA (counted: 8 stores + 1 E load issued after them),
    // read gst, data in regs (asm-only access; no compiler-inserted vmcnt here)
    f32x4 accA[4];
    asm volatile(
      "s_waitcnt vmcnt(9)\n\t"
      "ds_read_b128 %0, %4\n\t"
      "ds_read_b128 %1, %4 offset:1024\n\t"
      "ds_read_b128 %2, %4 offset:2048\n\t"
      "ds_read_b128 %3, %4 offset:3072\n\t"
      "s_waitcnt lgkmcnt(0)"
      : "=&v"(accA[0]), "=&v"(accA[1]), "=&v"(accA[2]), "=&v"(accA[3])
      : "v"(sb_addr) : "memory");
    // stage gates(t+1) into the same wave-private slots (slack row at t=999)
    {
      const float* gs = gsrc + gstep;
      gload_lds16(gs,          lbase);
      gload_lds16(gs +  1*256, lbase + 1*256);
      gload_lds16(gs + 16*256, lbase + 2*256);
      gload_lds16(gs + 17*256, lbase + 3*256);
    }
    gsrc += gstep;
    // phase A: h @ Wg_h  (tiles r0,r1,u0,u1)
    #pragma unroll
    for (int kt = 0; kt < 8; ++kt){
      half8 af = hA8[lrow*33 + kt*4 + lquad];
      if (kt == 0) {
        MFMA16_F(accA[0], af, wf[0][kt]);
        MFMA16_F(accA[1], af, wf[1][kt]);
        MFMA16_F(accA[2], af, wf[2][kt]);
        MFMA16_F(accA[3], af, wf[3][kt]);
      } else {
        MFMA16(accA[0], af, wf[0][kt]);
        MFMA16(accA[1], af, wf[1][kt]);
        MFMA16(accA[2], af, wf[2][kt]);
        MFMA16(accA[3], af, wf[3][kt]);
      }
    }
    // hazard fence: MFMA writes -> VALU reads of accA (register-tied, unskippable)
    asm volatile("s_nop 7\n\ts_nop 7"
                 : "+v"(accA[0]), "+v"(accA[1]), "+v"(accA[2]), "+v"(accA[3]));
    // ew1: u-gates (accA[2],[3] -> packed f16 aug), then r -> rhA
    half4 haug[2];
    #pragma unroll
    for (int p = 0; p < 2; ++p)
      #pragma unroll
      for (int i = 0; i < 4; ++i){
        float eu = __expf(-accA[2+p][i]);
        haug[p][i] = (_Float16)(ALPHA_C * __builtin_amdgcn_rcpf(1.0f + eu));
      }
    #pragma unroll
    for (int p = 0; p < 2; ++p){
      int ncol = 32*w + 16*p + lrow;
      #pragma unroll
      for (int i = 0; i < 4; ++i){
        float er = __expf(-accA[p][i]);
        float rg = __builtin_amdgcn_rcpf(1.0f + er);
        rhA[lquad*4+i][ncol] = (_Float16)(rg * hreg[p][i]);
      }
    }
    asm volatile("s_waitcnt lgkmcnt(0)\n\ts_barrier" ::: "memory");  // rhA visible
    // phase B: (r.*h) @ Wc_h  (tiles c0,c1); chain heads take literal-0 srcC
    f32x4 accB[2];
    #pragma unroll
    for (int kt = 0; kt < 8; ++kt){
      half8 af = rhA8[lrow*33 + kt*4 + lquad];
      if (kt == 0) {
        MFMA16_Z(accB[0], af, wf[4][kt]);
        MFMA16_Z(accB[1], af, wf[5][kt]);
      } else {
        MFMA16(accB[0], af, wf[4][kt]);
        MFMA16(accB[1], af, wf[5][kt]);
      }
    }
    asm volatile("s_nop 7\n\ts_nop 7" : "+v"(accB[0]), "+v"(accB[1]));
    // ew2: cand -> tanh -> leaky update; publish new h; 8 out stores (never drained)
    #pragma unroll
    for (int p = 0; p < 2; ++p){
      int ncol = 32*w + 16*p + lrow;
      #pragma unroll
      for (int i = 0; i < 4; ++i){
        float cand = accB[p][i] + (float)eh[p*4 + i];
        float e2 = __expf(2.0f*cand);
        float c  = (e2 - 1.0f)*__builtin_amdgcn_rcpf(e2 + 1.0f);
        float hold = hreg[p][i];
        float hnew = fmaf((float)haug[p][i], c - hold, hold);
        hreg[p][i] = hnew;
        hA[lquad*4+i][ncol] = (_Float16)hnew;
        outp[(size_t)i*NH + (size_t)p*16] = hnew;
      }
    }
    outp += (size_t)BATCH*NH;
    // E(t+1) into regs (after last use of eh; the 1 load in the vmcnt(9) window)
    gE += estep8;
    eh = gE[0];
    asm volatile("s_waitcnt lgkmcnt(0)\n\ts_barrier" ::: "memory");  // hA visible
  }
}

extern "C" void kernel_launch(void* const* d_in, const int* in_sizes, int n_in,
                              void* d_out, int out_size, void* d_ws, size_t ws_size,
                              hipStream_t stream) {
  (void)in_sizes; (void)n_in; (void)out_size; (void)ws_size;
  const float* x  = (const float*)d_in[0];
  const float* h0 = (const float*)d_in[1];
  const float* gk = (const float*)d_in[2];
  const float* gb = (const float*)d_in[3];
  const float* ck = (const float*)d_in[4];
  const float* cb = (const float*)d_in[5];
  const float* nz = (const float*)d_in[6];
  float* out = (float*)d_out;

  float* gxe = (float*)d_ws;                               // 525MB f32 gates
  unsigned short* gxeE   = (unsigned short*)(gxe + GXEG_F); // 131MB f16 E
  unsigned short* wpack  = gxeE + GXEE_US;
  unsigned short* wxpack = wpack + WPACK_US;

  k0_pack<<<1056, 256, 0, stream>>>(gk, ck, wpack, wxpack);
  k1_gxe<<<dim3(16, T_TOTAL), 256, 0, stream>>>(x, nz, gb, cb, wxpack, gxe, gxeE);
  k2_rec<<<16, 512, 0, stream>>>(h0, wpack, gxe, gxeE, out);
}